// Round 13
// baseline (117.227 us; speedup 1.0000x reference)
//
#include <hip/hip_runtime.h>
#include <stdint.h>

#define B_N    16384
#define NREG   64
#define KNB    5
#define SAMPLE 4096
#define NSUB   16
#define SUBLEN (SAMPLE / NSUB)       // 256 sample points per tau thread
#define NCH    32
#define CHLEN  (B_N / NCH)           // 512 scan points per spatial thread
#define MRGBLK 256                   // merge blocks (64 q each, 4 threads/q)
#define SENT   0xFFFF

static __device__ __forceinline__ float inf32() { return __int_as_float(0x7f800000); }
static __device__ __forceinline__ float med3(float a, float b, float c) {
    return __builtin_amdgcn_fmed3f(a, b, c);
}

// values-only sorted-insert into ascending s0..s4 (4 med3 + 1 min)
#define MINS5(nv)                      \
    {                                  \
        s4 = med3(s3, s4, (nv));       \
        s3 = med3(s2, s3, (nv));       \
        s2 = med3(s1, s2, (nv));       \
        s1 = med3(s0, s1, (nv));       \
        s0 = fminf(s0, (nv));          \
    }

// indexed flat 5-slot sorted-insert; strict < => ties keep earlier insert (smaller j)
#define INS5(nv, jj)                                                        \
    {                                                                       \
        bool c4 = (nv) < s4, c3 = (nv) < s3, c2 = (nv) < s2,                \
             c1 = (nv) < s1, c0 = (nv) < s0;                                \
        s4 = c3 ? s3 : (c4 ? (nv) : s4);  i4 = c3 ? i3 : (c4 ? (jj) : i4);  \
        s3 = c2 ? s2 : (c3 ? (nv) : s3);  i3 = c2 ? i2 : (c3 ? (jj) : i3);  \
        s2 = c1 ? s1 : (c2 ? (nv) : s2);  i2 = c1 ? i1 : (c2 ? (jj) : i2);  \
        s1 = c0 ? s0 : (c1 ? (nv) : s1);  i1 = c0 ? i0 : (c1 ? (jj) : i1);  \
        s0 = c0 ? (nv) : s0;              i0 = c0 ? (jj) : i0;              \
    }

// ---- K1: tau_scan + fused tau-merge tail (blocks 0..1023) + region/pre (1024..1087) ----
__global__ __launch_bounds__(256) void scan_region_kernel(const float* __restrict__ c,
                                                          const float* __restrict__ x,
                                                          const int* __restrict__ ids,
                                                          float4* __restrict__ pre,
                                                          float* __restrict__ tauv,
                                                          float* __restrict__ tau,
                                                          float* __restrict__ wsreg,
                                                          int* __restrict__ subcount) {
    const int blk = blockIdx.x;
    const int tid = threadIdx.x;

    if (blk >= 1024) {
        // ---- region partials + pre[] writes (concurrent with tau_scan) ----
        const int r = blk - 1024;
        {
            int j = r * 256 + tid;
            float jx = x[3 * j + 0], jy = x[3 * j + 1], jz = x[3 * j + 2];
            pre[j] = make_float4(-2.f * jx, -2.f * jy, -2.f * jz,
                                 jx * jx + jy * jy + jz * jz);
        }
        float cnt = 0.f, sx = 0.f, sy = 0.f, sz = 0.f, sxx = 0.f, syy = 0.f, szz = 0.f;
        for (int i = tid; i < B_N; i += 256) {
            int id = ids[i];
            float m = (id == r) ? 1.0f : 0.0f;
            float px = c[3 * i + 0], py = c[3 * i + 1], pz = c[3 * i + 2];
            cnt += m;
            sx += m * px;  sy += m * py;  sz += m * pz;
            sxx += m * px * px;  syy += m * py * py;  szz += m * pz * pz;
        }
        for (int off = 32; off > 0; off >>= 1) {
            cnt += __shfl_down(cnt, off);
            sx  += __shfl_down(sx, off);
            sy  += __shfl_down(sy, off);
            sz  += __shfl_down(sz, off);
            sxx += __shfl_down(sxx, off);
            syy += __shfl_down(syy, off);
            szz += __shfl_down(szz, off);
        }
        __shared__ float sb[4][7];
        const int lane = tid & 63, w = tid >> 6;
        if (lane == 0) {
            sb[w][0] = cnt; sb[w][1] = sx; sb[w][2] = sy; sb[w][3] = sz;
            sb[w][4] = sxx; sb[w][5] = syy; sb[w][6] = szz;
        }
        __syncthreads();
        if (tid == 0) {
            float C = 0, SX = 0, SY = 0, SZ = 0, SXX = 0, SYY = 0, SZZ = 0;
            for (int i = 0; i < 4; i++) {
                C += sb[i][0]; SX += sb[i][1]; SY += sb[i][2]; SZ += sb[i][3];
                SXX += sb[i][4]; SYY += sb[i][5]; SZZ += sb[i][6];
            }
            float safe = fmaxf(C, 1.0f);
            float mx = SX / safe, my = SY / safe, mz = SZ / safe;
            float ssc = (SXX - C * mx * mx) + (SYY - C * my * my) + (SZZ - C * mz * mz);
            float npairs = C * (C - 1.0f) * 0.5f;
            float denom = fmaxf(npairs, 1.0f) * 3.0f;
            wsreg[r] = (C > 1.0f) ? (2.0f * ssc / denom) : 0.0f;
        }
        return;
    }

    // ---- tau_scan: LDS tile built inline from x ----
    __shared__ float4 tile[SUBLEN];           // 4 KiB
    const int qb = blk & 63;
    const int sub = blk >> 6;                 // 0..15
    const int q = qb * 256 + tid;
    const int j0 = sub * SUBLEN;
    {
        int j = j0 + tid;
        float jx = x[3 * j + 0], jy = x[3 * j + 1], jz = x[3 * j + 2];
        tile[tid] = make_float4(-2.f * jx, -2.f * jy, -2.f * jz,
                                jx * jx + jy * jy + jz * jz);
    }
    const float qx = x[3 * q + 0], qy = x[3 * q + 1], qz = x[3 * q + 2];
    __syncthreads();

    {
        float s0 = inf32(), s1 = inf32(), s2 = inf32(), s3 = inf32(), s4 = inf32();
        if (qb != sub) {                      // block-uniform: no self-point here
            for (int jb = 0; jb < SUBLEN; jb += 8) {
                float dt[8];
#pragma unroll
                for (int u = 0; u < 8; ++u) {
                    float4 pj = tile[jb + u]; // wave-uniform -> LDS broadcast
                    dt[u] = fmaf(pj.x, qx, fmaf(pj.y, qy, fmaf(pj.z, qz, pj.w)));
                }
#pragma unroll
                for (int u = 0; u < 8; ++u) MINS5(dt[u]);
            }
        } else {                              // self-point sub-tile (qb < 16 only)
            for (int jb = 0; jb < SUBLEN; jb += 8) {
                float dt[8];
#pragma unroll
                for (int u = 0; u < 8; ++u) {
                    float4 pj = tile[jb + u];
                    dt[u] = fmaf(pj.x, qx, fmaf(pj.y, qy, fmaf(pj.z, qz, pj.w)));
                }
#pragma unroll
                for (int u = 0; u < 8; ++u) {
                    float nv = ((j0 + jb + u) != q) ? dt[u] : inf32();
                    MINS5(nv);
                }
            }
        }
        tauv[(sub * 5 + 0) * B_N + q] = s0;   // transposed: coalesced in q
        tauv[(sub * 5 + 1) * B_N + q] = s1;
        tauv[(sub * 5 + 2) * B_N + q] = s2;
        tauv[(sub * 5 + 3) * B_N + q] = s3;
        tauv[(sub * 5 + 4) * B_N + q] = s4;
    }

    // ---- fused tau-merge: 16th sub-block per qb merges 80 values -> bumped tau[q] ----
    __shared__ int lastsub;
    __syncthreads();                          // tauv stores issued by whole block
    if (tid == 0) {
        __threadfence();                      // release
        int old = atomicAdd(&subcount[qb], 1);
        lastsub = (old == NSUB - 1);
    }
    __syncthreads();
    if (!lastsub) return;
    if (tid == 0) __threadfence();            // acquire
    __syncthreads();

    {
        float s0 = inf32(), s1 = inf32(), s2 = inf32(), s3 = inf32(), s4 = inf32();
#pragma unroll 8
        for (int n = 0; n < NSUB * 5; ++n) {
            float v = tauv[n * B_N + q];      // coalesced
            MINS5(v);
        }
        int b = __float_as_int(s4);           // bump 1 ulp: admit d == tau ties
        b += (b >= 0) ? 1 : -1;
        tau[q] = __int_as_float(b);
    }
}

// ---- K2: tau-filtered scan of an LDS-staged 512-chunk ----
__global__ __launch_bounds__(256) void spatial_kernel(const float4* __restrict__ pre,
                                                      const float* __restrict__ tau,
                                                      unsigned short* __restrict__ cand) {
    __shared__ float4 tile[CHLEN];            // 8 KiB
    const int tid = threadIdx.x;
    const int qb = blockIdx.x & 63;
    const int ch = blockIdx.x >> 6;           // 0..31
    const int q = qb * 256 + tid;
    const int jbase = ch * CHLEN;

#pragma unroll
    for (int i = 0; i < CHLEN / 256; ++i)     // coalesced tile load
        tile[tid + i * 256] = pre[jbase + tid + i * 256];

    const float4 pq = pre[q];
    const float qx = -0.5f * pq.x, qy = -0.5f * pq.y, qz = -0.5f * pq.z;
    const float t = tau[q];
    __syncthreads();

    float s0 = t, s1 = t, s2 = t, s3 = t, s4 = t;
    int i0 = SENT, i1 = SENT, i2 = SENT, i3 = SENT, i4 = SENT;

    for (int jb = 0; jb < CHLEN; jb += 8) {
        float dt[8];
#pragma unroll
        for (int u = 0; u < 8; ++u) {
            float4 pj = tile[jb + u];         // wave-uniform -> LDS broadcast
            dt[u] = fmaf(pj.x, qx, fmaf(pj.y, qy, fmaf(pj.z, qz, pj.w)));
        }
        // group-of-8 min prefilter: ONE ballot/branch per 8 points
        float m = fminf(fminf(fminf(dt[0], dt[1]), fminf(dt[2], dt[3])),
                        fminf(fminf(dt[4], dt[5]), fminf(dt[6], dt[7])));
        if (__builtin_expect(__any(m < s4), 0)) {
#pragma unroll
            for (int u = 0; u < 8; ++u) {
                if (__any(dt[u] < s4)) {      // exact per-u path, order preserved
                    int j = jbase + jb + u;
                    bool p = (dt[u] < s4) && (j != q);
                    float nv = p ? dt[u] : inf32();
                    INS5(nv, j);
                }
            }
        }
    }
    cand[(ch * 5 + 0) * B_N + q] = (unsigned short)i0;   // transposed: coalesced
    cand[(ch * 5 + 1) * B_N + q] = (unsigned short)i1;
    cand[(ch * 5 + 2) * B_N + q] = (unsigned short)i2;
    cand[(ch * 5 + 3) * B_N + q] = (unsigned short)i3;
    cand[(ch * 5 + 4) * B_N + q] = (unsigned short)i4;
}

// ---- K3: final merge (4 threads/q) + c-loss + last-block finalize ----
__global__ __launch_bounds__(256) void merge_kernel(const float* __restrict__ c,
                                                    const float4* __restrict__ pre,
                                                    const unsigned short* __restrict__ cand,
                                                    const float* __restrict__ wsreg,
                                                    float* __restrict__ spart,
                                                    int* __restrict__ counter,
                                                    float* __restrict__ out) {
    const int tid = threadIdx.x;
    const int blk = blockIdx.x;
    const int qloc = tid >> 2;                // 0..63
    const int part = tid & 3;                 // 0..3 (chunks part*8 .. part*8+7)
    const int q = blk * 64 + qloc;
    const float4 pq = pre[q];
    const float qx = -0.5f * pq.x, qy = -0.5f * pq.y, qz = -0.5f * pq.z;

    __shared__ float dm[64][4][5];
    __shared__ unsigned short im[64][4][5];

    {
        float s0 = inf32(), s1 = inf32(), s2 = inf32(), s3 = inf32(), s4 = inf32();
        int i0 = SENT & 0x3FFF, i1 = i0, i2 = i0, i3 = i0, i4 = i0;
        const int n0 = part * (NCH / 4) * 5;  // 40 slots, chunk-ascending
#pragma unroll 8
        for (int n = n0; n < n0 + (NCH / 4) * 5; ++n) {
            int cd = (int)cand[n * B_N + q];
            int safe = cd & 0x3FFF;           // SENT -> valid addr, masked below
            float4 pj = pre[safe];
            float d = fmaf(pj.x, qx, fmaf(pj.y, qy, fmaf(pj.z, qz, pj.w)));
            float nv = (cd != SENT) ? d : inf32();
            INS5(nv, safe);
        }
        dm[qloc][part][0] = s0; im[qloc][part][0] = (unsigned short)i0;
        dm[qloc][part][1] = s1; im[qloc][part][1] = (unsigned short)i1;
        dm[qloc][part][2] = s2; im[qloc][part][2] = (unsigned short)i2;
        dm[qloc][part][3] = s3; im[qloc][part][3] = (unsigned short)i3;
        dm[qloc][part][4] = s4; im[qloc][part][4] = (unsigned short)i4;
    }
    __syncthreads();

    float acc = 0.f;
    if (part == 0) {
        float s0 = inf32(), s1 = inf32(), s2 = inf32(), s3 = inf32(), s4 = inf32();
        int i0 = 0, i1 = 0, i2 = 0, i3 = 0, i4 = 0;
#pragma unroll
        for (int p = 0; p < 4; ++p)           // ascending p = ascending chunks
#pragma unroll
            for (int k = 0; k < 5; ++k) {
                float nv = dm[qloc][p][k];
                int jj = (int)im[qloc][p][k];
                INS5(nv, jj);
            }
        const float cx = c[3 * q + 0], cy = c[3 * q + 1], cz = c[3 * q + 2];
        int ks[5] = {i0, i1, i2, i3, i4};
#pragma unroll
        for (int n = 0; n < KNB; ++n) {
            int nb = ks[n];
            float dx = cx - c[3 * nb + 0];
            float dy = cy - c[3 * nb + 1];
            float dz = cz - c[3 * nb + 2];
            acc += dx * dx + dy * dy + dz * dz;
        }
    }
    // acc nonzero on lanes == 0 mod 4; offsets 32,16,8,4 sum them onto lane 0
    acc += __shfl_down(acc, 32);
    acc += __shfl_down(acc, 16);
    acc += __shfl_down(acc, 8);
    acc += __shfl_down(acc, 4);
    __shared__ float wsum[4];
    __shared__ int last;
    const int lane = tid & 63, w = tid >> 6;
    if (lane == 0) wsum[w] = acc;
    __syncthreads();
    if (tid == 0) {
        float bs = wsum[0] + wsum[1] + wsum[2] + wsum[3];
        atomicExch(&spart[blk], bs);          // device-scope visible store
        __threadfence();
        int old = atomicAdd(counter, 1);
        last = (old == MRGBLK - 1);
    }
    __syncthreads();
    if (last) {
        // fixed-order reduction => bitwise deterministic regardless of which block runs it
        float s = atomicAdd(&spart[tid], 0.0f);          // device-scope read, 256 partials
        float r = (tid < NREG) ? wsreg[tid] : 0.f;
        for (int off = 32; off > 0; off >>= 1) {
            s += __shfl_down(s, off);
            r += __shfl_down(r, off);
        }
        __shared__ float fb[4];
        if (lane == 0) fb[w] = s;
        __syncthreads();
        if (tid == 0) {
            float S = fb[0] + fb[1] + fb[2] + fb[3];
            float spatial_mean = S / (float)(B_N * KNB);
            out[0] = 0.02f * r + 0.0005f * (spatial_mean / 3.0f);
        }
    }
}

extern "C" void kernel_launch(void* const* d_in, const int* in_sizes, int n_in,
                              void* d_out, int out_size, void* d_ws, size_t ws_size,
                              hipStream_t stream) {
    const float* c  = (const float*)d_in[0];   // c_points   [16384,3] f32
    const float* x  = (const float*)d_in[1];   // coords_std [16384,3] f32
    const int* ids  = (const int*)d_in[2];     // region_ids [16384] i32
    float* out = (float*)d_out;

    char* ws = (char*)d_ws;
    float4* pre = (float4*)ws;                                        // 256 KiB
    float* tauv = (float*)(ws + (size_t)B_N * 16);                    // 5.25 MiB
    unsigned short* cand =
        (unsigned short*)((char*)tauv + (size_t)NSUB * 5 * B_N * 4);  // 5.25 MiB
    float* tau = (float*)((char*)cand + (size_t)NCH * 5 * B_N * 2);   // 64 KiB
    float* wsreg = tau + B_N;                                         // 64 f
    float* spart = wsreg + NREG;                                      // 256 f
    int* subcount = (int*)(spart + MRGBLK);                           // 64 i
    int* counter = subcount + 64;                                     // 1 i

    // subcount is produced AND consumed inside K1 -> must be pre-zeroed each call
    hipMemsetAsync(subcount, 0, 65 * sizeof(int), stream);

    hipLaunchKernelGGL(scan_region_kernel, dim3(1088), dim3(256), 0, stream,
                       c, x, ids, pre, tauv, tau, wsreg, subcount);
    hipLaunchKernelGGL(spatial_kernel, dim3(64 * NCH), dim3(256), 0, stream,
                       pre, tau, cand);
    hipLaunchKernelGGL(merge_kernel, dim3(MRGBLK), dim3(256), 0, stream, c, pre, cand,
                       wsreg, spart, counter, out);
}

// Round 14
// 90.953 us; speedup vs baseline: 1.2889x; 1.2889x over previous
//
#include <hip/hip_runtime.h>
#include <stdint.h>

#define B_N    16384
#define NREG   64
#define KNB    5
#define SAMPLE 4096
#define NSUB   16
#define SUBLEN (SAMPLE / NSUB)       // 256 sample points per tau thread
#define NCH    32
#define CHLEN  (B_N / NCH)           // 512 scan points per spatial thread
#define MRGBLK 256                   // merge blocks (64 q each, 4 threads/q)
#define SENT   0xFFFF

static __device__ __forceinline__ float inf32() { return __int_as_float(0x7f800000); }
static __device__ __forceinline__ float med3(float a, float b, float c) {
    return __builtin_amdgcn_fmed3f(a, b, c);
}

// values-only sorted-insert into ascending s0..s4 (4 med3 + 1 min)
#define MINS5(nv)                      \
    {                                  \
        s4 = med3(s3, s4, (nv));       \
        s3 = med3(s2, s3, (nv));       \
        s2 = med3(s1, s2, (nv));       \
        s1 = med3(s0, s1, (nv));       \
        s0 = fminf(s0, (nv));          \
    }

// indexed flat 5-slot sorted-insert; strict < => ties keep earlier insert (smaller j)
#define INS5(nv, jj)                                                        \
    {                                                                       \
        bool c4 = (nv) < s4, c3 = (nv) < s3, c2 = (nv) < s2,                \
             c1 = (nv) < s1, c0 = (nv) < s0;                                \
        s4 = c3 ? s3 : (c4 ? (nv) : s4);  i4 = c3 ? i3 : (c4 ? (jj) : i4);  \
        s3 = c2 ? s2 : (c3 ? (nv) : s3);  i3 = c2 ? i2 : (c3 ? (jj) : i3);  \
        s2 = c1 ? s1 : (c2 ? (nv) : s2);  i2 = c1 ? i1 : (c2 ? (jj) : i2);  \
        s1 = c0 ? s0 : (c1 ? (nv) : s1);  i1 = c0 ? i0 : (c1 ? (jj) : i1);  \
        s0 = c0 ? (nv) : s0;              i0 = c0 ? (jj) : i0;              \
    }

// ---- K1: tau_scan (blocks 0..1023) + region/pre (blocks 1024..1087), NO fences ----
__global__ __launch_bounds__(256) void scan_region_kernel(const float* __restrict__ c,
                                                          const float* __restrict__ x,
                                                          const int* __restrict__ ids,
                                                          float4* __restrict__ pre,
                                                          float* __restrict__ tauv,
                                                          float* __restrict__ wsreg,
                                                          int* __restrict__ counter) {
    const int blk = blockIdx.x;
    const int tid = threadIdx.x;

    if (blk >= 1024) {
        // ---- region partials + pre[] writes (concurrent with tau_scan) ----
        const int r = blk - 1024;
        if (r == 0 && tid == 0) *counter = 0;     // re-zero merge counter each call
        {
            int j = r * 256 + tid;
            float jx = x[3 * j + 0], jy = x[3 * j + 1], jz = x[3 * j + 2];
            pre[j] = make_float4(-2.f * jx, -2.f * jy, -2.f * jz,
                                 jx * jx + jy * jy + jz * jz);
        }
        float cnt = 0.f, sx = 0.f, sy = 0.f, sz = 0.f, sxx = 0.f, syy = 0.f, szz = 0.f;
        for (int i = tid; i < B_N; i += 256) {
            int id = ids[i];
            float m = (id == r) ? 1.0f : 0.0f;
            float px = c[3 * i + 0], py = c[3 * i + 1], pz = c[3 * i + 2];
            cnt += m;
            sx += m * px;  sy += m * py;  sz += m * pz;
            sxx += m * px * px;  syy += m * py * py;  szz += m * pz * pz;
        }
        for (int off = 32; off > 0; off >>= 1) {
            cnt += __shfl_down(cnt, off);
            sx  += __shfl_down(sx, off);
            sy  += __shfl_down(sy, off);
            sz  += __shfl_down(sz, off);
            sxx += __shfl_down(sxx, off);
            syy += __shfl_down(syy, off);
            szz += __shfl_down(szz, off);
        }
        __shared__ float sb[4][7];
        const int lane = tid & 63, w = tid >> 6;
        if (lane == 0) {
            sb[w][0] = cnt; sb[w][1] = sx; sb[w][2] = sy; sb[w][3] = sz;
            sb[w][4] = sxx; sb[w][5] = syy; sb[w][6] = szz;
        }
        __syncthreads();
        if (tid == 0) {
            float C = 0, SX = 0, SY = 0, SZ = 0, SXX = 0, SYY = 0, SZZ = 0;
            for (int i = 0; i < 4; i++) {
                C += sb[i][0]; SX += sb[i][1]; SY += sb[i][2]; SZ += sb[i][3];
                SXX += sb[i][4]; SYY += sb[i][5]; SZZ += sb[i][6];
            }
            float safe = fmaxf(C, 1.0f);
            float mx = SX / safe, my = SY / safe, mz = SZ / safe;
            float ssc = (SXX - C * mx * mx) + (SYY - C * my * my) + (SZZ - C * mz * mz);
            float npairs = C * (C - 1.0f) * 0.5f;
            float denom = fmaxf(npairs, 1.0f) * 3.0f;
            wsreg[r] = (C > 1.0f) ? (2.0f * ssc / denom) : 0.0f;
        }
        return;
    }

    // ---- tau_scan: LDS tile built inline from x ----
    __shared__ float4 tile[SUBLEN];           // 4 KiB
    const int qb = blk & 63;
    const int sub = blk >> 6;                 // 0..15
    const int q = qb * 256 + tid;
    const int j0 = sub * SUBLEN;
    {
        int j = j0 + tid;
        float jx = x[3 * j + 0], jy = x[3 * j + 1], jz = x[3 * j + 2];
        tile[tid] = make_float4(-2.f * jx, -2.f * jy, -2.f * jz,
                                jx * jx + jy * jy + jz * jz);
    }
    const float qx = x[3 * q + 0], qy = x[3 * q + 1], qz = x[3 * q + 2];
    __syncthreads();

    float s0 = inf32(), s1 = inf32(), s2 = inf32(), s3 = inf32(), s4 = inf32();

    if (qb != sub) {                          // block-uniform: no self-point in tile
        for (int jb = 0; jb < SUBLEN; jb += 8) {
            float dt[8];
#pragma unroll
            for (int u = 0; u < 8; ++u) {
                float4 pj = tile[jb + u];     // wave-uniform -> LDS broadcast
                dt[u] = fmaf(pj.x, qx, fmaf(pj.y, qy, fmaf(pj.z, qz, pj.w)));
            }
#pragma unroll
            for (int u = 0; u < 8; ++u) MINS5(dt[u]);
        }
    } else {                                  // self-point sub-tile (qb < 16 only)
        for (int jb = 0; jb < SUBLEN; jb += 8) {
            float dt[8];
#pragma unroll
            for (int u = 0; u < 8; ++u) {
                float4 pj = tile[jb + u];
                dt[u] = fmaf(pj.x, qx, fmaf(pj.y, qy, fmaf(pj.z, qz, pj.w)));
            }
#pragma unroll
            for (int u = 0; u < 8; ++u) {
                float nv = ((j0 + jb + u) != q) ? dt[u] : inf32();   // self-exclusion
                MINS5(nv);
            }
        }
    }
    tauv[(sub * 5 + 0) * B_N + q] = s0;       // transposed: coalesced in q
    tauv[(sub * 5 + 1) * B_N + q] = s1;
    tauv[(sub * 5 + 2) * B_N + q] = s2;
    tauv[(sub * 5 + 3) * B_N + q] = s3;
    tauv[(sub * 5 + 4) * B_N + q] = s4;
}

// ---- K2: merge 80 sample values -> bumped tau[q] (once per q) ----
__global__ __launch_bounds__(256) void tau_merge_kernel(const float* __restrict__ tauv,
                                                        float* __restrict__ tau) {
    const int q = blockIdx.x * 256 + threadIdx.x;
    float s0 = inf32(), s1 = inf32(), s2 = inf32(), s3 = inf32(), s4 = inf32();
#pragma unroll 8
    for (int n = 0; n < NSUB * 5; ++n) {
        float v = tauv[n * B_N + q];          // coalesced
        MINS5(v);
    }
    int b = __float_as_int(s4);               // bump 1 ulp: admit d == tau ties
    b += (b >= 0) ? 1 : -1;
    tau[q] = __int_as_float(b);
}

// ---- K3: tau-filtered scan of an LDS-staged 512-chunk ----
__global__ __launch_bounds__(256) void spatial_kernel(const float4* __restrict__ pre,
                                                      const float* __restrict__ tau,
                                                      unsigned short* __restrict__ cand) {
    __shared__ float4 tile[CHLEN];            // 8 KiB
    const int tid = threadIdx.x;
    const int qb = blockIdx.x & 63;
    const int ch = blockIdx.x >> 6;           // 0..31
    const int q = qb * 256 + tid;
    const int jbase = ch * CHLEN;

#pragma unroll
    for (int i = 0; i < CHLEN / 256; ++i)     // coalesced tile load
        tile[tid + i * 256] = pre[jbase + tid + i * 256];

    const float4 pq = pre[q];
    const float qx = -0.5f * pq.x, qy = -0.5f * pq.y, qz = -0.5f * pq.z;
    const float t = tau[q];
    __syncthreads();

    float s0 = t, s1 = t, s2 = t, s3 = t, s4 = t;
    int i0 = SENT, i1 = SENT, i2 = SENT, i3 = SENT, i4 = SENT;

    for (int jb = 0; jb < CHLEN; jb += 8) {
        float dt[8];
#pragma unroll
        for (int u = 0; u < 8; ++u) {
            float4 pj = tile[jb + u];         // wave-uniform -> LDS broadcast
            dt[u] = fmaf(pj.x, qx, fmaf(pj.y, qy, fmaf(pj.z, qz, pj.w)));
        }
        // group-of-8 min prefilter: ONE ballot/branch per 8 points
        float m = fminf(fminf(fminf(dt[0], dt[1]), fminf(dt[2], dt[3])),
                        fminf(fminf(dt[4], dt[5]), fminf(dt[6], dt[7])));
        if (__builtin_expect(__any(m < s4), 0)) {
#pragma unroll
            for (int u = 0; u < 8; ++u) {
                if (__any(dt[u] < s4)) {      // exact per-u path, order preserved
                    int j = jbase + jb + u;
                    bool p = (dt[u] < s4) && (j != q);
                    float nv = p ? dt[u] : inf32();
                    INS5(nv, j);
                }
            }
        }
    }
    cand[(ch * 5 + 0) * B_N + q] = (unsigned short)i0;   // transposed: coalesced
    cand[(ch * 5 + 1) * B_N + q] = (unsigned short)i1;
    cand[(ch * 5 + 2) * B_N + q] = (unsigned short)i2;
    cand[(ch * 5 + 3) * B_N + q] = (unsigned short)i3;
    cand[(ch * 5 + 4) * B_N + q] = (unsigned short)i4;
}

// ---- K4: final merge (4 threads/q) + c-loss + last-block finalize ----
__global__ __launch_bounds__(256) void merge_kernel(const float* __restrict__ c,
                                                    const float4* __restrict__ pre,
                                                    const unsigned short* __restrict__ cand,
                                                    const float* __restrict__ wsreg,
                                                    float* __restrict__ spart,
                                                    int* __restrict__ counter,
                                                    float* __restrict__ out) {
    const int tid = threadIdx.x;
    const int blk = blockIdx.x;
    const int qloc = tid >> 2;                // 0..63
    const int part = tid & 3;                 // 0..3 (chunks part*8 .. part*8+7)
    const int q = blk * 64 + qloc;
    const float4 pq = pre[q];
    const float qx = -0.5f * pq.x, qy = -0.5f * pq.y, qz = -0.5f * pq.z;

    __shared__ float dm[64][4][5];
    __shared__ unsigned short im[64][4][5];

    {
        float s0 = inf32(), s1 = inf32(), s2 = inf32(), s3 = inf32(), s4 = inf32();
        int i0 = SENT & 0x3FFF, i1 = i0, i2 = i0, i3 = i0, i4 = i0;
        const int n0 = part * (NCH / 4) * 5;  // 40 slots, chunk-ascending
#pragma unroll 8
        for (int n = n0; n < n0 + (NCH / 4) * 5; ++n) {
            int cd = (int)cand[n * B_N + q];
            int safe = cd & 0x3FFF;           // SENT -> valid addr, masked below
            float4 pj = pre[safe];
            float d = fmaf(pj.x, qx, fmaf(pj.y, qy, fmaf(pj.z, qz, pj.w)));
            float nv = (cd != SENT) ? d : inf32();
            INS5(nv, safe);
        }
        dm[qloc][part][0] = s0; im[qloc][part][0] = (unsigned short)i0;
        dm[qloc][part][1] = s1; im[qloc][part][1] = (unsigned short)i1;
        dm[qloc][part][2] = s2; im[qloc][part][2] = (unsigned short)i2;
        dm[qloc][part][3] = s3; im[qloc][part][3] = (unsigned short)i3;
        dm[qloc][part][4] = s4; im[qloc][part][4] = (unsigned short)i4;
    }
    __syncthreads();

    float acc = 0.f;
    if (part == 0) {
        float s0 = inf32(), s1 = inf32(), s2 = inf32(), s3 = inf32(), s4 = inf32();
        int i0 = 0, i1 = 0, i2 = 0, i3 = 0, i4 = 0;
#pragma unroll
        for (int p = 0; p < 4; ++p)           // ascending p = ascending chunks
#pragma unroll
            for (int k = 0; k < 5; ++k) {
                float nv = dm[qloc][p][k];
                int jj = (int)im[qloc][p][k];
                INS5(nv, jj);
            }
        const float cx = c[3 * q + 0], cy = c[3 * q + 1], cz = c[3 * q + 2];
        int ks[5] = {i0, i1, i2, i3, i4};
#pragma unroll
        for (int n = 0; n < KNB; ++n) {
            int nb = ks[n];
            float dx = cx - c[3 * nb + 0];
            float dy = cy - c[3 * nb + 1];
            float dz = cz - c[3 * nb + 2];
            acc += dx * dx + dy * dy + dz * dz;
        }
    }
    // acc nonzero on lanes == 0 mod 4; offsets 32,16,8,4 sum them onto lane 0
    acc += __shfl_down(acc, 32);
    acc += __shfl_down(acc, 16);
    acc += __shfl_down(acc, 8);
    acc += __shfl_down(acc, 4);
    __shared__ float wsum[4];
    __shared__ int last;
    const int lane = tid & 63, w = tid >> 6;
    if (lane == 0) wsum[w] = acc;
    __syncthreads();
    if (tid == 0) {
        float bs = wsum[0] + wsum[1] + wsum[2] + wsum[3];
        atomicExch(&spart[blk], bs);          // device-scope visible store
        __threadfence();
        int old = atomicAdd(counter, 1);
        last = (old == MRGBLK - 1);
    }
    __syncthreads();
    if (last) {
        // fixed-order reduction => bitwise deterministic regardless of which block runs it
        float s = atomicAdd(&spart[tid], 0.0f);          // device-scope read, 256 partials
        float r = (tid < NREG) ? wsreg[tid] : 0.f;
        for (int off = 32; off > 0; off >>= 1) {
            s += __shfl_down(s, off);
            r += __shfl_down(r, off);
        }
        __shared__ float fb[4];
        if (lane == 0) fb[w] = s;
        __syncthreads();
        if (tid == 0) {
            float S = fb[0] + fb[1] + fb[2] + fb[3];
            float spatial_mean = S / (float)(B_N * KNB);
            out[0] = 0.02f * r + 0.0005f * (spatial_mean / 3.0f);
        }
    }
}

extern "C" void kernel_launch(void* const* d_in, const int* in_sizes, int n_in,
                              void* d_out, int out_size, void* d_ws, size_t ws_size,
                              hipStream_t stream) {
    const float* c  = (const float*)d_in[0];   // c_points   [16384,3] f32
    const float* x  = (const float*)d_in[1];   // coords_std [16384,3] f32
    const int* ids  = (const int*)d_in[2];     // region_ids [16384] i32
    float* out = (float*)d_out;

    char* ws = (char*)d_ws;
    float4* pre = (float4*)ws;                                        // 256 KiB
    float* tauv = (float*)(ws + (size_t)B_N * 16);                    // 5.25 MiB
    unsigned short* cand =
        (unsigned short*)((char*)tauv + (size_t)NSUB * 5 * B_N * 4);  // 5.25 MiB
    float* tau = (float*)((char*)cand + (size_t)NCH * 5 * B_N * 2);   // 64 KiB
    float* wsreg = tau + B_N;                                         // 64 f
    float* spart = wsreg + NREG;                                      // 256 f
    int* counter = (int*)(spart + MRGBLK);                            // 1 int

    hipLaunchKernelGGL(scan_region_kernel, dim3(1088), dim3(256), 0, stream,
                       c, x, ids, pre, tauv, wsreg, counter);
    hipLaunchKernelGGL(tau_merge_kernel, dim3(64), dim3(256), 0, stream, tauv, tau);
    hipLaunchKernelGGL(spatial_kernel, dim3(64 * NCH), dim3(256), 0, stream,
                       pre, tau, cand);
    hipLaunchKernelGGL(merge_kernel, dim3(MRGBLK), dim3(256), 0, stream, c, pre, cand,
                       wsreg, spart, counter, out);
}